// Round 6
// baseline (126.479 us; speedup 1.0000x reference)
//
#include <hip/hip_runtime.h>
#include <hip/hip_cooperative_groups.h>
#include <cmath>

namespace cg = cooperative_groups;

// Problem constants (match reference)
#define BB 4
#define NN 48
#define PP (NN * NN)   // 2304 (x,y) pairs per plane
#define NP 49          // padded stride for transposed LDS tiles (gcd(49,32)=1)
#define TT 33
#define RR 16
#define NC 80
#define NI 5
#define NEG (-1000.0f)

#define NBLK 320       // one block per (b,c); co-resident (2 blocks/CU: 74.5KB LDS)
#define NTH  192       // 3 waves; 16 x-tiles (3 wide) x 12 y-tiles (4 wide)

// ---------------------------------------------------------------------------
// Single cooperative kernel:
//  Phase 1 (block = (b,c)): gather H0T/H1/H2 from trans (conflict-free LDS
//    layouts), two max-plus 48x48 products with 3x4 register tiles (k-paired
//    so fmax(acc, fmax(t0,t1)) folds to v_max3_f32), epilogue exp(S)*w -> sw.
//  grid.sync()
//  Phase 2: combine — 4 threads per (b,x,y), each one 4-triple quad; all sw
//    reads 64-wide coalesced; mask/out via int4/float4.
// Rationale: R2-R5 showed total time is insensitive to kernel structure
// (kernel compute ~8-12 us vs 34 us controllable budget) -> per-dispatch
// overhead dominates; collapse 3 dispatches to 1.
// ---------------------------------------------------------------------------
__global__ __launch_bounds__(NTH) void fused_kernel(
    const float* __restrict__ trans,    // [B,N,N,T]
    const int*   __restrict__ rules,    // [Nc,3]
    const float* __restrict__ weights,  // [Nc]
    const float* __restrict__ biases,   // [R]
    const int*   __restrict__ mask,     // [B,N,N,R]
    float*       __restrict__ out,      // [B,N,N,R]
    float*       __restrict__ sw)       // [B,Nc,N,N] scratch
{
    cg::grid_group grid = cg::this_grid();

    __shared__ float H0T[NN * NP];  // A of product 1, transposed [k][x]
    __shared__ float H1 [PP];       // B of product 1, [k][y]
    __shared__ float H2 [PP];       // B of product 2, [k][y]
    __shared__ float S1T[NN * NP];  // A of product 2, transposed [k][x]

    // ================= Phase 1: chain DP =================
    {
        const int bc = blockIdx.x;
        const int b  = bc / NC;
        const int c  = bc - b * NC;

        const int r0 = rules[c * 3 + 0];
        const int r1 = rules[c * 3 + 1];
        const int r2 = rules[c * 3 + 2];

        const float* tb = trans + (size_t)b * PP * TT;

        // Gather hop planes. H0T: lanes step k -> LDS addr stride 49,
        // gcd(49,32)=1 -> conflict-free. H1/H2 writes consecutive.
        for (int i = threadIdx.x; i < PP; i += NTH) {
            const int x = i / NN;
            const int k = i - x * NN;
            const size_t base = (size_t)i * TT;
            H0T[k * NP + x] = tb[base + r0];
            H1[i]           = tb[base + r1];
            H2[i]           = tb[base + r2];
        }
        __syncthreads();

        const int tx = threadIdx.x & 15;   // 16 x-tiles (3 wide)
        const int ty = threadIdx.x >> 4;   // 12 y-tiles (4 wide)
        const int x0 = tx * 3;
        const int y0 = ty * 4;

        // ---- product 1: S1 = H0 (x) H1 ----
        float acc[3][4];
        #pragma unroll
        for (int jx = 0; jx < 3; ++jx)
            #pragma unroll
            for (int jy = 0; jy < 4; ++jy) acc[jx][jy] = -INFINITY;

        #pragma unroll 4
        for (int kp = 0; kp < NN / 2; ++kp) {
            const int k = kp * 2;
            float a0[3], a1[3];
            #pragma unroll
            for (int jx = 0; jx < 3; ++jx) {
                a0[jx] = H0T[k * NP + x0 + jx];
                a1[jx] = H0T[(k + 1) * NP + x0 + jx];
            }
            const float4 bv0 = *(const float4*)&H1[k * NN + y0];
            const float4 bv1 = *(const float4*)&H1[(k + 1) * NN + y0];
            const float b0[4] = {bv0.x, bv0.y, bv0.z, bv0.w};
            const float b1[4] = {bv1.x, bv1.y, bv1.z, bv1.w};
            #pragma unroll
            for (int jx = 0; jx < 3; ++jx)
                #pragma unroll
                for (int jy = 0; jy < 4; ++jy)
                    acc[jx][jy] = fmaxf(acc[jx][jy],
                                        fmaxf(a0[jx] + b0[jy], a1[jx] + b1[jy]));
        }

        // S1T[y][x]: lanes step tx -> addr stride 3, conflict-free
        #pragma unroll
        for (int jx = 0; jx < 3; ++jx)
            #pragma unroll
            for (int jy = 0; jy < 4; ++jy)
                S1T[(y0 + jy) * NP + x0 + jx] = acc[jx][jy];
        __syncthreads();

        // ---- product 2: S = S1 (x) H2, fused exp*weight epilogue ----
        float acc2[3][4];
        #pragma unroll
        for (int jx = 0; jx < 3; ++jx)
            #pragma unroll
            for (int jy = 0; jy < 4; ++jy) acc2[jx][jy] = -INFINITY;

        #pragma unroll 4
        for (int kp = 0; kp < NN / 2; ++kp) {
            const int k = kp * 2;
            float a0[3], a1[3];
            #pragma unroll
            for (int jx = 0; jx < 3; ++jx) {
                a0[jx] = S1T[k * NP + x0 + jx];
                a1[jx] = S1T[(k + 1) * NP + x0 + jx];
            }
            const float4 bv0 = *(const float4*)&H2[k * NN + y0];
            const float4 bv1 = *(const float4*)&H2[(k + 1) * NN + y0];
            const float b0[4] = {bv0.x, bv0.y, bv0.z, bv0.w};
            const float b1[4] = {bv1.x, bv1.y, bv1.z, bv1.w};
            #pragma unroll
            for (int jx = 0; jx < 3; ++jx)
                #pragma unroll
                for (int jy = 0; jy < 4; ++jy)
                    acc2[jx][jy] = fmaxf(acc2[jx][jy],
                                         fmaxf(a0[jx] + b0[jy], a1[jx] + b1[jy]));
        }

        const float wgt = weights[c];
        float* outp = sw + (size_t)bc * PP;
        #pragma unroll
        for (int jx = 0; jx < 3; ++jx) {
            float4 o;
            o.x = __expf(acc2[jx][0]) * wgt;
            o.y = __expf(acc2[jx][1]) * wgt;
            o.z = __expf(acc2[jx][2]) * wgt;
            o.w = __expf(acc2[jx][3]) * wgt;
            *(float4*)&outp[(x0 + jx) * NN + y0] = o;
        }
    }

    grid.sync();   // all sw writes visible grid-wide

    // ================= Phase 2: combine =================
    {
        const int tid = blockIdx.x * NTH + threadIdx.x;   // 61440 threads
        if (tid < BB * PP * 4) {                          // 36864 items
            // group of 256 threads: 64 consecutive p-lanes x 4 triple-quads;
            // within a 64-lane wave quad is constant, lane = p -> coalesced.
            const int quad = (tid >> 6) & 3;
            const int pl   = (tid >> 8) * 64 + (tid & 63);  // (b,p) linear
            const int b = pl / PP;
            const int p = pl - b * PP;

            const float* base = sw + (size_t)b * NC * PP + p;

            float acc[4];
            #pragma unroll
            for (int tt = 0; tt < 4; ++tt) {
                const int t = quad * 4 + tt;
                float s = biases[t];
                #pragma unroll
                for (int i = 0; i < NI; ++i)
                    s += base[(size_t)(t * NI + i) * PP];
                acc[tt] = s;
            }

            const int4 m = *(const int4*)(mask + (size_t)pl * RR + quad * 4);
            float4 o;
            o.x = (m.x == 0) ? acc[0] : NEG;
            o.y = (m.y == 0) ? acc[1] : NEG;
            o.z = (m.z == 0) ? acc[2] : NEG;
            o.w = (m.w == 0) ? acc[3] : NEG;
            *(float4*)(out + (size_t)pl * RR + quad * 4) = o;
        }
    }
}

extern "C" void kernel_launch(void* const* d_in, const int* in_sizes, int n_in,
                              void* d_out, int out_size, void* d_ws, size_t ws_size,
                              hipStream_t stream)
{
    const float* trans   = (const float*)d_in[0];  // [B,N,N,T] f32
    const int*   mask    = (const int*)  d_in[1];  // [B,N,N,R] i32
    const int*   rules   = (const int*)  d_in[2];  // [Nc,3]    i32
    const float* weights = (const float*)d_in[3];  // [Nt,Ni]   f32
    const float* biases  = (const float*)d_in[4];  // [Nt]      f32
    float* out = (float*)d_out;
    float* sw  = (float*)d_ws;                     // [B,Nc,N,N] = 2.95 MB

    void* args[] = { (void*)&trans, (void*)&rules, (void*)&weights,
                     (void*)&biases, (void*)&mask, (void*)&out, (void*)&sw };
    hipLaunchCooperativeKernel((const void*)fused_kernel,
                               dim3(NBLK), dim3(NTH), args, 0, stream);
}

// Round 7
// 83.017 us; speedup vs baseline: 1.5235x; 1.5235x over previous
//
#include <hip/hip_runtime.h>
#include <cmath>

// Problem constants (match reference)
#define BB 4
#define NN 48
#define PP (NN * NN)   // 2304 (x,y) pairs per plane
#define TT 33
#define RR 16
#define NC 80
#define NI 5
#define NEG (-1000.0f)

// fused kernel decomposition
#define XS 24          // x-range per block (x-half)
#define XP 25          // padded stride for [k][x_local] tiles (gcd(25,32)=1)
#define NTH 384        // 6 waves; 24 x-rows x 16 y-triplets, 3 outs/thread

// ---------------------------------------------------------------------------
// Kernel 0: transpose trans [B, 2304, 33] -> tpose [B, 33, 2304] so every
// hop-plane is a contiguous 9 KB block (cheap coalesced staging; R4 verified
// the gather-free staging path).
// ---------------------------------------------------------------------------
__global__ __launch_bounds__(256) void transpose_kernel(
    const float* __restrict__ trans,   // [B, 2304, 33]
    float*       __restrict__ tpose)   // [B, 33, 2304]
{
    __shared__ float tile[64 * TT];    // 64 p x 33 t
    const int blk = blockIdx.x;        // B * 36
    const int b   = blk / 36;
    const int p0  = (blk - b * 36) * 64;

    const float4* src = (const float4*)(trans + ((size_t)b * PP + p0) * TT);
    for (int j = threadIdx.x; j < 64 * TT / 4; j += 256)
        ((float4*)tile)[j] = src[j];
    __syncthreads();

    for (int j = threadIdx.x; j < TT * 64; j += 256) {
        const int t  = j >> 6;
        const int pl = j & 63;
        tpose[((size_t)b * TT + t) * PP + p0 + pl] = tile[pl * TT + t];
    }
}

// ---------------------------------------------------------------------------
// Kernel 1: fused scorer. Block = (b, triple, x-half); 384 threads.
//   For each of the triple's 5 chains: stage H0T (x-slice, transposed into
//   [k][x_local]), H1, H2 (full planes) from tpose; two max-plus products
//   (k-paired -> v_max3_f32); accumulate w_i * exp(S) into registers.
//   Epilogue: + bias, mask-select, write out[b,x,y,t] directly.
//   Thread -> (xl = tid>>4, y0 = (tid&15)*3): S1T/H0T reads are 16-lane
//   broadcasts (free); H1/H2 reads stride 3 words (conflict-free); S1T
//   writes stride 75 words (gcd(75,32)=1, conflict-free).
// ---------------------------------------------------------------------------
__global__ __launch_bounds__(NTH) void fused_scorer(
    const float* __restrict__ tpose,    // [B, 33, 2304]
    const int*   __restrict__ rules,    // [Nc,3]
    const float* __restrict__ weights,  // [Nt,Ni] flat
    const float* __restrict__ biases,   // [Nt]
    const int*   __restrict__ mask,     // [B,N,N,R]
    float*       __restrict__ out)      // [B,N,N,R]
{
    __shared__ float H0T[NN * XP];  // [k][x_local] of product 1
    __shared__ float H1 [PP];       // [k][y] of product 1
    __shared__ float H2 [PP];       // [k][y] of product 2
    __shared__ float S1T[NN * XP];  // [k2][x_local] of product 2

    const int blk = blockIdx.x;     // 128 = 4 b x 16 t x 2 xh
    const int xh  = blk & 1;
    const int bt  = blk >> 1;
    const int b   = bt >> 4;
    const int t   = bt & 15;
    const int xbase = xh * XS;

    const int xl = threadIdx.x >> 4;        // 0..23 (x row within half)
    const int yt = threadIdx.x & 15;        // 16 y-triplets
    const int y0 = yt * 3;

    float acc_out[3] = {0.0f, 0.0f, 0.0f};  // sum_i w_i * exp(S_i) for 3 y's

    for (int ci = 0; ci < NI; ++ci) {
        const int c  = t * NI + ci;
        const int r0 = rules[c * 3 + 0];
        const int r1 = rules[c * 3 + 1];
        const int r2 = rules[c * 3 + 2];
        const float w = weights[c];

        const float* p0 = tpose + ((size_t)b * TT + r0) * PP + xbase * NN;
        const float* p1 = tpose + ((size_t)b * TT + r1) * PP;
        const float* p2 = tpose + ((size_t)b * TT + r2) * PP;

        __syncthreads();   // previous iteration's LDS reads complete

        // Stage: H1/H2 full planes (coalesced float4); H0 x-slice scattered
        // into [k][xl] (4 b32 writes, stride 25 words -> conflict-free).
        for (int j = threadIdx.x; j < PP / 4; j += NTH) {
            ((float4*)H1)[j] = ((const float4*)p1)[j];
            ((float4*)H2)[j] = ((const float4*)p2)[j];
        }
        for (int j = threadIdx.x; j < XS * NN / 4; j += NTH) {
            const float4 v0 = ((const float4*)p0)[j];
            const int x = (4 * j) / NN;
            const int k = (4 * j) - x * NN;   // multiple of 4, same row
            H0T[(k + 0) * XP + x] = v0.x;
            H0T[(k + 1) * XP + x] = v0.y;
            H0T[(k + 2) * XP + x] = v0.z;
            H0T[(k + 3) * XP + x] = v0.w;
        }
        __syncthreads();

        // ---- product 1: S1[xl, y0..y0+2] ----
        float a0 = -INFINITY, a1 = -INFINITY, a2 = -INFINITY;
        #pragma unroll 4
        for (int kp = 0; kp < NN / 2; ++kp) {
            const int k = kp * 2;
            const float h0 = H0T[k * XP + xl];
            const float h1 = H0T[(k + 1) * XP + xl];
            a0 = fmaxf(a0, fmaxf(h0 + H1[k * NN + y0 + 0], h1 + H1[(k + 1) * NN + y0 + 0]));
            a1 = fmaxf(a1, fmaxf(h0 + H1[k * NN + y0 + 1], h1 + H1[(k + 1) * NN + y0 + 1]));
            a2 = fmaxf(a2, fmaxf(h0 + H1[k * NN + y0 + 2], h1 + H1[(k + 1) * NN + y0 + 2]));
        }
        // S1T[y][xl]: lane addr stride 75 words across yt -> conflict-free
        S1T[(y0 + 0) * XP + xl] = a0;
        S1T[(y0 + 1) * XP + xl] = a1;
        S1T[(y0 + 2) * XP + xl] = a2;
        __syncthreads();

        // ---- product 2: S[xl, y0..y0+2], accumulate w*exp ----
        float s0 = -INFINITY, s1 = -INFINITY, s2 = -INFINITY;
        #pragma unroll 4
        for (int kp = 0; kp < NN / 2; ++kp) {
            const int k = kp * 2;
            const float h0 = S1T[k * XP + xl];
            const float h1 = S1T[(k + 1) * XP + xl];
            s0 = fmaxf(s0, fmaxf(h0 + H2[k * NN + y0 + 0], h1 + H2[(k + 1) * NN + y0 + 0]));
            s1 = fmaxf(s1, fmaxf(h0 + H2[k * NN + y0 + 1], h1 + H2[(k + 1) * NN + y0 + 1]));
            s2 = fmaxf(s2, fmaxf(h0 + H2[k * NN + y0 + 2], h1 + H2[(k + 1) * NN + y0 + 2]));
        }
        acc_out[0] += w * __expf(s0);
        acc_out[1] += w * __expf(s1);
        acc_out[2] += w * __expf(s2);
    }

    // Epilogue: bias + mask + scattered (small) writes of 3 outputs.
    const float bias = biases[t];
    const int xg = xbase + xl;
    #pragma unroll
    for (int j = 0; j < 3; ++j) {
        const size_t oidx = ((size_t)(b * PP + xg * NN + y0 + j)) * RR + t;
        out[oidx] = (mask[oidx] == 0) ? (acc_out[j] + bias) : NEG;
    }
}

extern "C" void kernel_launch(void* const* d_in, const int* in_sizes, int n_in,
                              void* d_out, int out_size, void* d_ws, size_t ws_size,
                              hipStream_t stream)
{
    const float* trans   = (const float*)d_in[0];  // [B,N,N,T] f32
    const int*   mask    = (const int*)  d_in[1];  // [B,N,N,R] i32
    const int*   rules   = (const int*)  d_in[2];  // [Nc,3]    i32
    const float* weights = (const float*)d_in[3];  // [Nt,Ni]   f32
    const float* biases  = (const float*)d_in[4];  // [Nt]      f32
    float* out = (float*)d_out;

    float* tpose = (float*)d_ws;                   // [B,33,2304] = 1.22 MB

    transpose_kernel<<<BB * 36, 256, 0, stream>>>(trans, tpose);

    fused_scorer<<<BB * RR * 2, NTH, 0, stream>>>(tpose, rules, weights,
                                                  biases, mask, out);
}